// Round 1
// baseline (317.838 us; speedup 1.0000x reference)
//
#include <hip/hip_runtime.h>

// Problem constants (from reference setup_inputs): N=32, HW=4096, A=5, C=80
#define NBOX (32 * 4096 * 5)   // 655360 boxes
#define HWA  (4096 * 5)        // 20480 (prior repeats across N)
#define NCLS 80
#define THRESHOLD 0.5f

__global__ __launch_bounds__(256) void detector_kernel(
    const float4* __restrict__ box,     // NBOX float4 (cx,cy,w,h)
    const float*  __restrict__ conf,    // NBOX
    const float*  __restrict__ cls,     // NBOX * 80
    const float4* __restrict__ prior,   // HWA float4
    const unsigned int* __restrict__ fs_word,
    float4* __restrict__ box_out,       // NBOX float4
    float*  __restrict__ probs_out,     // NBOX
    float*  __restrict__ idx_out)       // NBOX (class index stored as float)
{
    const int tid = blockIdx.x * blockDim.x + threadIdx.x;
    if (tid >= NBOX) return;

    // feat_size: robust decode (accept int32 or float32 encoding of the scalar)
    const unsigned int w = *fs_word;
    const float fs  = (w < 1000000u) ? (float)w : __uint_as_float(w);
    const float inv = 1.0f / fs;   // fs = 64 -> exact

    // ---- box decode: center+prior -> corners, normalized ----
    const float4 b = box[tid];
    const float4 p = prior[tid % HWA];
    const float cx = b.x + p.x;
    const float cy = b.y + p.y;
    const float hx = (b.z * p.z) * 0.5f;
    const float hy = (b.w * p.w) * 0.5f;
    float4 corner;
    corner.x = (cx - hx) * inv;
    corner.y = (cy - hy) * inv;
    corner.z = (cx + hx) * inv;
    corner.w = (cy + hy) * inv;

    // ---- class scores: argmax of conf*cls, first-max-wins (np.argmax) ----
    const float cf = conf[tid];
    const float4* cv = (const float4*)(cls + (size_t)tid * NCLS);
    float m = -INFINITY;
    int   mi = 0;
#pragma unroll
    for (int j = 0; j < NCLS / 4; ++j) {
        const float4 v = cv[j];
        const float s0 = cf * v.x;
        const float s1 = cf * v.y;
        const float s2 = cf * v.z;
        const float s3 = cf * v.w;
        if (s0 > m) { m = s0; mi = 4 * j;     }
        if (s1 > m) { m = s1; mi = 4 * j + 1; }
        if (s2 > m) { m = s2; mi = 4 * j + 2; }
        if (s3 > m) { m = s3; mi = 4 * j + 3; }
    }

    const bool keep = (m > THRESHOLD);
    float4 bo;
    bo.x = keep ? corner.x : 0.0f;
    bo.y = keep ? corner.y : 0.0f;
    bo.z = keep ? corner.z : 0.0f;
    bo.w = keep ? corner.w : 0.0f;

    box_out[tid]   = bo;
    probs_out[tid] = keep ? m : 0.0f;
    idx_out[tid]   = (float)mi;
}

extern "C" void kernel_launch(void* const* d_in, const int* in_sizes, int n_in,
                              void* d_out, int out_size, void* d_ws, size_t ws_size,
                              hipStream_t stream) {
    const float4* box   = (const float4*)d_in[0];
    const float*  conf  = (const float*)d_in[1];
    const float*  cls   = (const float*)d_in[2];
    const float4* prior = (const float4*)d_in[3];
    const unsigned int* fs = (const unsigned int*)d_in[4];

    float* out = (float*)d_out;
    float4* box_out  = (float4*)out;                 // NBOX float4 = 4*NBOX floats
    float* probs_out = out + (size_t)4 * NBOX;       // NBOX floats
    float* idx_out   = probs_out + NBOX;             // NBOX floats

    const int threads = 256;
    const int blocks  = (NBOX + threads - 1) / threads;  // 2560
    detector_kernel<<<blocks, threads, 0, stream>>>(
        box, conf, cls, prior, fs, box_out, probs_out, idx_out);
}

// Round 2
// 302.924 us; speedup vs baseline: 1.0492x; 1.0492x over previous
//
#include <hip/hip_runtime.h>

// Problem constants (from reference setup_inputs): N=32, HW=4096, A=5, C=80
#define NBOX (32 * 4096 * 5)   // 655360 boxes
#define HWA  (4096 * 5)        // 20480 (prior repeats across N)
#define NCLS 80
#define BLOCK 128              // threads per block == boxes per block
#define ROW4 21                // padded LDS row: 21 float4 = 84 floats (80 + 4 pad)
                               // bank-group of ds_read_b128 = (5t+j) mod 8, gcd(5,8)=1 -> conflict-free
#define THRESHOLD 0.5f

__global__ __launch_bounds__(BLOCK) void detector_kernel(
    const float4* __restrict__ box,     // NBOX float4 (cx,cy,w,h)
    const float*  __restrict__ conf,    // NBOX
    const float*  __restrict__ cls,     // NBOX * 80
    const float4* __restrict__ prior,   // HWA float4
    const unsigned int* __restrict__ fs_word,
    float4* __restrict__ box_out,       // NBOX float4
    float*  __restrict__ probs_out,     // NBOX
    float*  __restrict__ idx_out)       // NBOX (class index stored as float)
{
    __shared__ float4 lds4[BLOCK * ROW4];   // 43008 B -> 3 blocks/CU

    const int t          = threadIdx.x;
    const int blockStart = blockIdx.x * BLOCK;
    const int tid        = blockStart + t;

    // ---- issue the per-box loads early so they overlap the staging loop ----
    const float4 b  = box[tid];
    const float4 p  = prior[tid % HWA];
    const float  cf = conf[tid];
    const unsigned int w = *fs_word;

    // ---- coalesced stage: 128 boxes x 80 floats = 2560 float4, stride-BLOCK ----
    const float4* cls4 = (const float4*)(cls + (size_t)blockStart * NCLS);
#pragma unroll
    for (int k = 0; k < NCLS / 4; ++k) {        // 20 iterations
        const int g   = k * BLOCK + t;          // 0..2559, coalesced across lanes
        const int bx  = g / 20;                 // owning box within block (magic-mul)
        const int off = g % 20;                 // float4 slot within row
        lds4[bx * ROW4 + off] = cls4[g];
    }

    // ---- box decode while staging is in flight ----
    const float fs  = (w < 1000000u) ? (float)w : __uint_as_float(w);
    const float inv = 1.0f / fs;                // fs = 64 -> exact
    const float cx = b.x + p.x;
    const float cy = b.y + p.y;
    const float hx = (b.z * p.z) * 0.5f;
    const float hy = (b.w * p.w) * 0.5f;
    float4 corner;
    corner.x = (cx - hx) * inv;
    corner.y = (cy - hy) * inv;
    corner.z = (cx + hx) * inv;
    corner.w = (cy + hy) * inv;

    __syncthreads();

    // ---- argmax of conf*cls from LDS, first-max-wins (np.argmax semantics) ----
    const float4* row = &lds4[t * ROW4];
    float m  = -INFINITY;
    int   mi = 0;
#pragma unroll
    for (int j = 0; j < NCLS / 4; ++j) {
        const float4 v = row[j];
        const float s0 = cf * v.x;
        const float s1 = cf * v.y;
        const float s2 = cf * v.z;
        const float s3 = cf * v.w;
        if (s0 > m) { m = s0; mi = 4 * j;     }
        if (s1 > m) { m = s1; mi = 4 * j + 1; }
        if (s2 > m) { m = s2; mi = 4 * j + 2; }
        if (s3 > m) { m = s3; mi = 4 * j + 3; }
    }

    const bool keep = (m > THRESHOLD);
    float4 bo;
    bo.x = keep ? corner.x : 0.0f;
    bo.y = keep ? corner.y : 0.0f;
    bo.z = keep ? corner.z : 0.0f;
    bo.w = keep ? corner.w : 0.0f;

    box_out[tid]   = bo;
    probs_out[tid] = keep ? m : 0.0f;
    idx_out[tid]   = (float)mi;
}

extern "C" void kernel_launch(void* const* d_in, const int* in_sizes, int n_in,
                              void* d_out, int out_size, void* d_ws, size_t ws_size,
                              hipStream_t stream) {
    const float4* box   = (const float4*)d_in[0];
    const float*  conf  = (const float*)d_in[1];
    const float*  cls   = (const float*)d_in[2];
    const float4* prior = (const float4*)d_in[3];
    const unsigned int* fs = (const unsigned int*)d_in[4];

    float* out = (float*)d_out;
    float4* box_out  = (float4*)out;                 // NBOX float4 = 4*NBOX floats
    float* probs_out = out + (size_t)4 * NBOX;       // NBOX floats
    float* idx_out   = probs_out + NBOX;             // NBOX floats

    const int blocks = NBOX / BLOCK;                 // 5120
    detector_kernel<<<blocks, BLOCK, 0, stream>>>(
        box, conf, cls, prior, fs, box_out, probs_out, idx_out);
}

// Round 3
// 302.640 us; speedup vs baseline: 1.0502x; 1.0009x over previous
//
#include <hip/hip_runtime.h>

// Problem constants (from reference setup_inputs): N=32, HW=4096, A=5, C=80
#define NBOX (32 * 4096 * 5)   // 655360 boxes
#define HWA  (4096 * 5)        // 20480 (prior repeats across N)
#define THRESHOLD 0.5f

// One wave = 16 boxes, 4 lanes per box, 5 float4 per lane.
// For quad q at iteration k, lanes read box q's bytes [64k,64k+64) -> one full
// 64B line per quad per instruction == perfect-coalescing line count. No LDS.
__global__ __launch_bounds__(256) void detector_kernel(
    const float4* __restrict__ box,     // NBOX float4 (cx,cy,w,h)
    const float*  __restrict__ conf,    // NBOX
    const float4* __restrict__ cls4,    // NBOX * 20 float4 (80 classes)
    const float4* __restrict__ prior,   // HWA float4
    const unsigned int* __restrict__ fs_word,
    float4* __restrict__ box_out,       // NBOX float4
    float*  __restrict__ probs_out,     // NBOX
    float*  __restrict__ idx_out)       // NBOX (class index stored as float)
{
    const int t       = threadIdx.x;
    const int lane    = t & 63;
    const int waveIdx = blockIdx.x * 4 + (t >> 6);
    const int boxBase = waveIdx * 16;          // 16 boxes per wave
    const int slot    = lane & 3;              // which float4 column group
    const int myBox   = boxBase + (lane >> 2); // scoring box for this lane

    // ---- issue decode loads early (redundant across quads; same cache lines) ----
    const int obox = boxBase + (lane & 15);    // output box for lanes 0..15
    const float4 b = box[obox];
    const float4 p = prior[obox % HWA];
    const unsigned int w = *fs_word;

    // conf of my scoring box (4 lanes share an address -> broadcast)
    const float cf = conf[myBox];

    // ---- class scores: 5 independent float4 loads per lane ----
    const float4* row = cls4 + (size_t)myBox * 20 + slot;
    const float4 v0 = row[0];
    const float4 v1 = row[4];
    const float4 v2 = row[8];
    const float4 v3 = row[12];
    const float4 v4 = row[16];

    // ---- per-lane argmax (indices ascend -> strict '>' = np.argmax first-wins) ----
    float m  = -1.0f;   // all products >= 0
    int   mi = 0;
    const int c0 = slot * 4;
#define STEP(V, K) { \
        const float s0 = cf * (V).x, s1 = cf * (V).y, s2 = cf * (V).z, s3 = cf * (V).w; \
        const int c = c0 + 16 * (K); \
        if (s0 > m) { m = s0; mi = c;     } \
        if (s1 > m) { m = s1; mi = c + 1; } \
        if (s2 > m) { m = s2; mi = c + 2; } \
        if (s3 > m) { m = s3; mi = c + 3; } }
    STEP(v0, 0) STEP(v1, 1) STEP(v2, 2) STEP(v3, 3) STEP(v4, 4)
#undef STEP

    // ---- quad butterfly reduce: pack (score_bits<<32)|(127-idx); scores>=0 so
    //      float bits are monotone; ties -> larger low word = smaller class idx ----
    unsigned long long packed =
        ((unsigned long long)__float_as_uint(m) << 32) | (unsigned int)(127 - mi);
    unsigned long long o;
    o = __shfl_xor(packed, 1, 64); if (o > packed) packed = o;
    o = __shfl_xor(packed, 2, 64); if (o > packed) packed = o;

    // gather quad q's result (lane 4q) into lane q for compact output
    const unsigned long long res = __shfl(packed, (lane & 15) * 4, 64);

    // ---- decode + output (lanes 0..15 of each wave) ----
    const float fs  = (w < 1000000u) ? (float)w : __uint_as_float(w);
    const float inv = 1.0f / fs;               // fs = 64 -> exact
    const float cx = b.x + p.x;
    const float cy = b.y + p.y;
    const float hx = (b.z * p.z) * 0.5f;
    const float hy = (b.w * p.w) * 0.5f;

    const float mm   = __uint_as_float((unsigned int)(res >> 32));
    const int   midx = 127 - (int)(res & 0x7Fu);
    const bool  keep = (mm > THRESHOLD);

    if (lane < 16) {
        float4 bo;
        bo.x = keep ? (cx - hx) * inv : 0.0f;
        bo.y = keep ? (cy - hy) * inv : 0.0f;
        bo.z = keep ? (cx + hx) * inv : 0.0f;
        bo.w = keep ? (cy + hy) * inv : 0.0f;
        box_out[obox]   = bo;
        probs_out[obox] = keep ? mm : 0.0f;
        idx_out[obox]   = (float)midx;
    }
}

extern "C" void kernel_launch(void* const* d_in, const int* in_sizes, int n_in,
                              void* d_out, int out_size, void* d_ws, size_t ws_size,
                              hipStream_t stream) {
    const float4* box   = (const float4*)d_in[0];
    const float*  conf  = (const float*)d_in[1];
    const float4* cls4  = (const float4*)d_in[2];
    const float4* prior = (const float4*)d_in[3];
    const unsigned int* fs = (const unsigned int*)d_in[4];

    float* out = (float*)d_out;
    float4* box_out  = (float4*)out;                 // NBOX float4 = 4*NBOX floats
    float* probs_out = out + (size_t)4 * NBOX;       // NBOX floats
    float* idx_out   = probs_out + NBOX;             // NBOX floats

    // 256 threads = 4 waves = 64 boxes per block
    const int blocks = NBOX / 64;                    // 10240
    detector_kernel<<<blocks, 256, 0, stream>>>(
        box, conf, cls4, prior, fs, box_out, probs_out, idx_out);
}